// Round 4
// baseline (207.601 us; speedup 1.0000x reference)
//
#include <hip/hip_runtime.h>

// Problem constants (b=2, c=64, h=w=96)
#define NPOS 9216
#define NB 2
#define CCH 64
#define VZP 40   // vz_lds row pitch in ushorts (80B -> 2-way-free bank pattern)

typedef __attribute__((ext_vector_type(8))) short short8;
typedef __attribute__((ext_vector_type(4))) float f32x4;

#define LOG2E 1.4426950408889634f

// f32 -> bf16 bits, round-to-nearest-even (scalar path, cold kernels only)
__device__ __forceinline__ ushort f2bf(float x) {
    unsigned u = __builtin_bit_cast(unsigned, x);
    u += 0x7FFFu + ((u >> 16) & 1u);
    return (ushort)(u >> 16);
}

__device__ __forceinline__ unsigned cvt_pk_bf16(float lo, float hi) {
    unsigned r;
    asm("v_cvt_pk_bf16_f32 %0, %1, %2" : "=v"(r) : "v"(lo), "v"(hi));
    return r;
}

// ---------------------------------------------------------------------------
// K1: 1x1 convs. q (pre-scaled by log2e),k -> bf16 [b][n][8]; v -> f32 [b][n][64];
// also out[b][c][n] = Y (residual base, folds the d2d memcpy).
// Block = 256 thr = 64 positions x 4 slices; 288 blocks.
// ---------------------------------------------------------------------------
__global__ __launch_bounds__(256) void qkv_kernel(
    const float* __restrict__ X, const float* __restrict__ Y,
    const float* __restrict__ Wq, const float* __restrict__ bq,
    const float* __restrict__ Wk, const float* __restrict__ bk,
    const float* __restrict__ Wv, const float* __restrict__ bv,
    ushort* __restrict__ qb, ushort* __restrict__ kb, float* __restrict__ v,
    float* __restrict__ out)
{
    __shared__ float wqkT[1024];   // [c][16]: o<8 Wq, o>=8 Wk
    __shared__ float wvT[4096];    // [c][64]
    int tid = threadIdx.x;
    for (int idx = tid; idx < 1024; idx += 256) {
        int c = idx >> 4, o = idx & 15;
        wqkT[idx] = (o < 8) ? Wq[o * 64 + c] : Wk[(o - 8) * 64 + c];
    }
    for (int idx = tid; idx < 4096; idx += 256) {
        int c = idx >> 6, o = idx & 63;
        wvT[idx] = Wv[o * 64 + c];
    }
    __syncthreads();

    int p = tid & 63, s = tid >> 6;          // s is wave-uniform
    int base = blockIdx.x * 64;
    int b = base / NPOS;
    int n = (base % NPOS) + p;

    float va[16], qk[8];
    #pragma unroll
    for (int o = 0; o < 16; ++o) va[o] = bv[s * 16 + o];
    #pragma unroll
    for (int o = 0; o < 8; ++o) qk[o] = 0.f;
    if (s == 0) {
        #pragma unroll
        for (int o = 0; o < 8; ++o) qk[o] = bq[o];
    } else if (s == 1) {
        #pragma unroll
        for (int o = 0; o < 8; ++o) qk[o] = bk[o];
    }

    const float* Xb = X + (size_t)b * CCH * NPOS + n;
    const float* Yb = Y + (size_t)b * CCH * NPOS + n;
    float* ob = out + (size_t)b * CCH * NPOS + n;
    for (int c = 0; c < 64; ++c) {
        float yv = Yb[(size_t)c * NPOS];
        ob[(size_t)c * NPOS] = yv;                 // residual base
        const float4* wv4 = (const float4*)(wvT + c * 64 + s * 16);
        #pragma unroll
        for (int o4 = 0; o4 < 4; ++o4) {
            float4 wv = wv4[o4];
            va[o4*4+0] += wv.x * yv; va[o4*4+1] += wv.y * yv;
            va[o4*4+2] += wv.z * yv; va[o4*4+3] += wv.w * yv;
        }
        if (s < 2) {
            float xv = Xb[(size_t)c * NPOS];
            const float4* wq4 = (const float4*)(wqkT + c * 16 + s * 8);
            float4 w0 = wq4[0], w1 = wq4[1];
            qk[0] += w0.x * xv; qk[1] += w0.y * xv;
            qk[2] += w0.z * xv; qk[3] += w0.w * xv;
            qk[4] += w1.x * xv; qk[5] += w1.y * xv;
            qk[6] += w1.z * xv; qk[7] += w1.w * xv;
        }
    }
    float4* vdst = (float4*)(v + ((size_t)b * NPOS + n) * 64 + s * 16);
    #pragma unroll
    for (int o4 = 0; o4 < 4; ++o4)
        vdst[o4] = make_float4(va[o4*4], va[o4*4+1], va[o4*4+2], va[o4*4+3]);
    if (s < 2) {
        if (s == 0) {   // q: fold log2e so both passes use raw exp2
            #pragma unroll
            for (int o = 0; o < 8; ++o) qk[o] *= LOG2E;
        }
        short8 row;
        #pragma unroll
        for (int o = 0; o < 8; ++o) row[o] = (short)f2bf(qk[o]);
        ushort* dst = (s == 0 ? qb : kb) + ((size_t)b * NPOS + n) * 8;
        *(short8*)dst = row;
    }
}

// ---------------------------------------------------------------------------
// K2: Z[b][j] = sum_i exp2(q_i . k_j) via MFMA (q carries the log2e).
// Wave owns 16 j (A-frag, g==0 lanes); streams q rows (B-frag).
// D layout: col=i=lane&15, row=j=4g+r. grid (144 j64-blocks, 4 i-quarters, b).
// ---------------------------------------------------------------------------
__global__ __launch_bounds__(256) void zpass_kernel(
    const ushort* __restrict__ qb, const ushort* __restrict__ kb,
    float* __restrict__ Z)
{
    int tid = threadIdx.x;
    int w = tid >> 6, l = tid & 63;
    int il = l & 15, g = l >> 4;
    int b = blockIdx.z;
    int jb = blockIdx.x * 64 + w * 16;
    const short8 zero8 = {0,0,0,0,0,0,0,0};
    const f32x4 cz = {0.f,0.f,0.f,0.f};

    short8 kf = zero8;
    if (g == 0) kf = *(const short8*)(kb + ((size_t)b * NPOS + jb + il) * 8);

    float za[4] = {0.f, 0.f, 0.f, 0.f};
    const ushort* qrow = qb + ((size_t)b * NPOS + blockIdx.y * 2304 + il) * 8;
    for (int is = 0; is < 144; ++is) {
        short8 qf = *(const short8*)(qrow + (size_t)is * 128);
        if (g != 0) qf = zero8;
        f32x4 sv = __builtin_amdgcn_mfma_f32_16x16x32_bf16(kf, qf, cz, 0, 0, 0);
        za[0] += __builtin_amdgcn_exp2f(sv[0]);
        za[1] += __builtin_amdgcn_exp2f(sv[1]);
        za[2] += __builtin_amdgcn_exp2f(sv[2]);
        za[3] += __builtin_amdgcn_exp2f(sv[3]);
    }
    #pragma unroll
    for (int r = 0; r < 4; ++r) {
        float x = za[r];
        x += __shfl_xor(x, 1, 16);
        x += __shfl_xor(x, 2, 16);
        x += __shfl_xor(x, 4, 16);
        x += __shfl_xor(x, 8, 16);
        za[r] = x;
    }
    if (il == 0) {
        #pragma unroll
        for (int r = 0; r < 4; ++r)
            atomicAdd(&Z[(size_t)b * NPOS + jb + g * 4 + r], za[r]);
    }
}

// ---------------------------------------------------------------------------
// K3: VzT[b][c][n] = bf16( v[b][n][c] / Z[b][n] )  (scale + transpose)
// ---------------------------------------------------------------------------
__global__ __launch_bounds__(256) void scalevT_kernel(
    const float* __restrict__ v, const float* __restrict__ Z,
    ushort* __restrict__ VzT)
{
    int tid = threadIdx.x;
    int p = tid & 63, s = tid >> 6;
    int base = blockIdx.x * 64;
    int b = base / NPOS;
    int n = (base % NPOS) + p;
    float rz = 1.0f / Z[(size_t)b * NPOS + n];
    const float4* vr = (const float4*)(v + ((size_t)b * NPOS + n) * 64 + s * 16);
    ushort* dst = VzT + (size_t)b * CCH * NPOS + n;
    #pragma unroll
    for (int q4 = 0; q4 < 4; ++q4) {
        float4 a = vr[q4];
        size_t c0 = s * 16 + q4 * 4;
        dst[(c0 + 0) * NPOS] = f2bf(a.x * rz);
        dst[(c0 + 1) * NPOS] = f2bf(a.y * rz);
        dst[(c0 + 2) * NPOS] = f2bf(a.z * rz);
        dst[(c0 + 3) * NPOS] = f2bf(a.w * rz);
    }
}

// ---------------------------------------------------------------------------
// K4: X^T[c][i] += sum_j exp2(q_i.k_j) * VzT[c][j], MFMA both GEMMs.
// Block = 4 waves x 16 i; 72 j32-steps; VzT tile (80B-pitch rows, 2-way-free)
// double-buffered in LDS; P via swizzled per-wave LDS roundtrip.
// grid (144 i-blocks, 4 j-splits, b); atomicAdd into Y-preloaded out.
// ---------------------------------------------------------------------------
__global__ __launch_bounds__(256) void pass2_kernel(
    const ushort* __restrict__ qb, const ushort* __restrict__ kb,
    const ushort* __restrict__ VzT, float* __restrict__ out)
{
    __shared__ ushort vz_lds[2][64 * VZP];  // [64 c][32 j], pitch 40
    __shared__ ushort p_lds[4][512];        // per-wave [16 i][32 j], slot-XOR swizzled
    int tid = threadIdx.x;
    int w = tid >> 6, l = tid & 63;
    int il = l & 15, g = l >> 4;
    int b = blockIdx.z;
    int ibase = blockIdx.x * 64 + w * 16;
    int j0 = blockIdx.y * 2304;

    const short8 zero8 = {0,0,0,0,0,0,0,0};
    const f32x4 cz = {0.f,0.f,0.f,0.f};

    short8 qf = zero8;
    if (g == 0) qf = *(const short8*)(qb + ((size_t)b * NPOS + ibase + il) * 8);

    f32x4 acc[4];
    #pragma unroll
    for (int cg = 0; cg < 4; ++cg) acc[cg] = cz;

    const ushort* kbb = kb + (size_t)b * NPOS * 8;
    // staging map: thread t -> (c = t>>2, jslot = t&3), 16B each
    int sc = tid >> 2, sslot = tid & 3;
    const ushort* vsrc = VzT + (size_t)b * CCH * NPOS + (size_t)sc * NPOS + j0 + sslot * 8;

    // prologue: stage tile 0
    *(float4*)&vz_lds[0][sc * VZP + sslot * 8] = *(const float4*)vsrc;
    __syncthreads();

    int swz = (il >> 1) & 3;
    ushort* pw = p_lds[w];

    for (int st = 0; st < 72; ++st) {
        int jb = j0 + st * 32;
        int cur = st & 1;
        bool more = (st + 1) < 72;
        float4 nv = {0.f,0.f,0.f,0.f};
        if (more) nv = *(const float4*)(vsrc + (size_t)(st + 1) * 32);   // prefetch

        // S^T = K.Q^T (two 16-j MFMAs), K padded 8->32
        short8 kf0 = zero8, kf1 = zero8;
        if (g == 0) {
            kf0 = *(const short8*)(kbb + (size_t)(jb + il) * 8);
            kf1 = *(const short8*)(kbb + (size_t)(jb + 16 + il) * 8);
        }
        f32x4 s0 = __builtin_amdgcn_mfma_f32_16x16x32_bf16(kf0, qf, cz, 0, 0, 0);
        f32x4 s1 = __builtin_amdgcn_mfma_f32_16x16x32_bf16(kf1, qf, cz, 0, 0, 0);

        // exp2 -> packed bf16 -> P_lds (row il; logical slot, XOR swz)
        int rowoff = il * 32 + (g & 1) * 4;
        {
            int stored = ((g >> 1) ^ swz);
            unsigned u01 = cvt_pk_bf16(__builtin_amdgcn_exp2f(s0[0]),
                                       __builtin_amdgcn_exp2f(s0[1]));
            unsigned u23 = cvt_pk_bf16(__builtin_amdgcn_exp2f(s0[2]),
                                       __builtin_amdgcn_exp2f(s0[3]));
            *(unsigned*)&pw[rowoff + stored * 8 + 0] = u01;
            *(unsigned*)&pw[rowoff + stored * 8 + 2] = u23;
        }
        {
            int stored = ((2 | (g >> 1)) ^ swz);
            unsigned u01 = cvt_pk_bf16(__builtin_amdgcn_exp2f(s1[0]),
                                       __builtin_amdgcn_exp2f(s1[1]));
            unsigned u23 = cvt_pk_bf16(__builtin_amdgcn_exp2f(s1[2]),
                                       __builtin_amdgcn_exp2f(s1[3]));
            *(unsigned*)&pw[rowoff + stored * 8 + 0] = u01;
            *(unsigned*)&pw[rowoff + stored * 8 + 2] = u23;
        }

        // B-frag: P^T[j=8g+e][i=il]  (same-wave LDS read-back, swizzled slot)
        short8 pf = *(short8*)&pw[il * 32 + ((g ^ swz) * 8)];

        // PV: X^T[c][i] += VzT_tile . P^T   (4 c-groups)
        #pragma unroll
        for (int cg = 0; cg < 4; ++cg) {
            short8 af = *(short8*)&vz_lds[cur][(cg * 16 + il) * VZP + g * 8];
            acc[cg] = __builtin_amdgcn_mfma_f32_16x16x32_bf16(af, pf, acc[cg], 0, 0, 0);
        }

        // write prefetched tile to the other buffer; one barrier per step
        if (more) *(float4*)&vz_lds[cur ^ 1][sc * VZP + sslot * 8] = nv;
        __syncthreads();
    }

    // epilogue: D row = c-local = g*4+r, col = i = il
    float* ob = out + (size_t)b * CCH * NPOS + ibase + il;
    #pragma unroll
    for (int cg = 0; cg < 4; ++cg) {
        #pragma unroll
        for (int r = 0; r < 4; ++r) {
            int c = cg * 16 + g * 4 + r;
            atomicAdd(ob + (size_t)c * NPOS, acc[cg][r]);
        }
    }
}

extern "C" void kernel_launch(void* const* d_in, const int* in_sizes, int n_in,
                              void* d_out, int out_size, void* d_ws, size_t ws_size,
                              hipStream_t stream) {
    const float* X  = (const float*)d_in[0];
    const float* Y  = (const float*)d_in[1];
    const float* Wq = (const float*)d_in[2];
    const float* bq = (const float*)d_in[3];
    const float* Wk = (const float*)d_in[4];
    const float* bk = (const float*)d_in[5];
    const float* Wv = (const float*)d_in[6];
    const float* bv = (const float*)d_in[7];

    char* ws = (char*)d_ws;
    ushort* qb  = (ushort*)(ws);             // 2*9216*8 bf16   = 294912 B
    ushort* kbw = (ushort*)(ws + 294912);    // 294912 B
    ushort* VzT = (ushort*)(ws + 589824);    // 2*64*9216 bf16  = 2359296 B
    float*  v   = (float*) (ws + 2949120);   // 2*9216*64 f32   = 4718592 B
    float*  Z   = (float*) (ws + 7667712);   // 18432 f32       = 73728 B

    hipMemsetAsync(Z, 0, (size_t)NB * NPOS * sizeof(float), stream);

    qkv_kernel<<<288, 256, 0, stream>>>(X, Y, Wq, bq, Wk, bk, Wv, bv,
                                        qb, kbw, v, (float*)d_out);
    zpass_kernel<<<dim3(144, 4, NB), 256, 0, stream>>>(qb, kbw, Z);
    scalevT_kernel<<<288, 256, 0, stream>>>(v, Z, VzT);
    pass2_kernel<<<dim3(144, 4, NB), 256, 0, stream>>>(qb, kbw, VzT, (float*)d_out);
}